// Round 1
// baseline (2280.758 us; speedup 1.0000x reference)
//
#include <hip/hip_runtime.h>
#include <math.h>

#define D1 768
#define D2R 385
#define NF 295680   // 768*385
#define KNUM 4
#define NB 8
#define NC 256
#define HW 64

// ws layout (floats):
//   bufA [0 .. 2365440)  : scattered spectrum (4,768,385) complex; reused as SW (4,768,768) real
//   bufY [2365440 .. )   : stage-A output (4,768,385) complex
#define SPEC_FLOATS 2365440

// ---------------- scatter: dft_weight -> dense half-spectrum -------------
__global__ __launch_bounds__(256) void scatter_kernel(
    const float* __restrict__ dw, const int* __restrict__ fh,
    const int* __restrict__ fw, float* __restrict__ spec) {
  int i = blockIdx.x * 256 + threadIdx.x;  // 0..NF-1 (grid.x = 1155 exact)
  int k = blockIdx.y;
  const float2 v = ((const float2*)dw)[(size_t)k * NF + i];
  int h = fh[i], w = fw[i];
  ((float2*)spec)[((size_t)k * D1 + h) * D2R + w] = v;
}

// ---------------- stage A: complex ifft along axis 0 (length 768) --------
// Y[k][m][c] = (wgt_c/768^2) * sum_h spec[k][h][c] * e^{+2pi i h m/768}
__global__ __launch_bounds__(256) void stageA_kernel(
    const float* __restrict__ spec, float* __restrict__ Y) {
  __shared__ float Es[32 * 64 * 2];  // [h][m] complex
  __shared__ float Ss[32 * 32 * 2];  // [h][c] complex
  int t = threadIdx.x;
  int c0 = blockIdx.x * 32;
  int m0 = blockIdx.y * 64;
  int k = blockIdx.z;
  int tx = t & 31, ty = t >> 5;
  float accre[8] = {0.f, 0.f, 0.f, 0.f, 0.f, 0.f, 0.f, 0.f};
  float accim[8] = {0.f, 0.f, 0.f, 0.f, 0.f, 0.f, 0.f, 0.f};

  for (int kt = 0; kt < 24; ++kt) {
    int h0 = kt * 32;
    __syncthreads();
#pragma unroll
    for (int p = 0; p < 4; ++p) {  // load S tile (32h x 32c)
      int idx = t + 256 * p;
      int h = idx >> 5, c = idx & 31;
      float2 v = make_float2(0.f, 0.f);
      if (c0 + c < D2R)
        v = ((const float2*)spec)[((size_t)k * D1 + h0 + h) * D2R + c0 + c];
      ((float2*)Ss)[h * 32 + c] = v;
    }
#pragma unroll
    for (int p = 0; p < 8; ++p) {  // generate E tile (32h x 64m)
      int idx = t + 256 * p;
      int h = idx >> 6, m = idx & 63;
      int tt = ((h0 + h) * (m0 + m)) % 768;
      float th = (float)tt * 0.008181230868723419f;  // 2pi/768
      float s, c2;
      sincosf(th, &s, &c2);
      ((float2*)Es)[h * 64 + m] = make_float2(c2, s);
    }
    __syncthreads();
#pragma unroll 4
    for (int h = 0; h < 32; ++h) {
      float2 S = ((float2*)Ss)[h * 32 + tx];
#pragma unroll
      for (int j = 0; j < 8; ++j) {
        float2 E = ((float2*)Es)[h * 64 + ty + 8 * j];
        accre[j] = fmaf(S.x, E.x, accre[j]);
        accre[j] = fmaf(-S.y, E.y, accre[j]);
        accim[j] = fmaf(S.x, E.y, accim[j]);
        accim[j] = fmaf(S.y, E.x, accim[j]);
      }
    }
  }
  int c = c0 + tx;
  if (c < D2R) {
    // fold irfft Hermitian weights (2 for interior bins) and 1/768^2
    float scale = (c == 0 || c == D2R - 1) ? 1.6954210069444445e-6f
                                           : 3.390842013888889e-6f;
#pragma unroll
    for (int j = 0; j < 8; ++j) {
      int m = m0 + ty + 8 * j;
      ((float2*)Y)[((size_t)k * D1 + m) * D2R + c] =
          make_float2(accre[j] * scale, accim[j] * scale);
    }
  }
}

// ---------------- stage B: real irfft along axis 1 (385 -> 768) ----------
// SW[k][m][n] = sum_c ( ReY'[m][c] cos(2pi c n/768) - ImY'[m][c] sin(...) )
__global__ __launch_bounds__(256) void stageB_kernel(
    const float* __restrict__ Y, float* __restrict__ SW) {
  __shared__ float Ys[32 * 65 * 2];  // [c][m] complex, padded stride 65
  __shared__ float Tw[32 * 64 * 2];  // [c][n] (cos, sin)
  int t = threadIdx.x;
  int n0 = blockIdx.x * 64;
  int m0 = blockIdx.y * 64;
  int k = blockIdx.z;
  int tx = t & 31, ty = t >> 5;
  float acc0[8] = {0.f, 0.f, 0.f, 0.f, 0.f, 0.f, 0.f, 0.f};
  float acc1[8] = {0.f, 0.f, 0.f, 0.f, 0.f, 0.f, 0.f, 0.f};

  for (int kt = 0; kt < 13; ++kt) {
    int cb = kt * 32;
    __syncthreads();
#pragma unroll
    for (int p = 0; p < 8; ++p) {  // load Y tile transposed -> [c][m]
      int idx = t + 256 * p;
      int m = idx >> 5, c = idx & 31;
      float2 v = make_float2(0.f, 0.f);
      if (cb + c < D2R)
        v = ((const float2*)Y)[((size_t)k * D1 + m0 + m) * D2R + cb + c];
      ((float2*)Ys)[c * 65 + m] = v;
    }
#pragma unroll
    for (int p = 0; p < 8; ++p) {  // generate twiddle tile [c][n]
      int idx = t + 256 * p;
      int c = idx >> 6, n = idx & 63;
      int tt = ((cb + c) * (n0 + n)) % 768;
      float th = (float)tt * 0.008181230868723419f;
      float s, cc;
      sincosf(th, &s, &cc);
      ((float2*)Tw)[c * 64 + n] = make_float2(cc, s);
    }
    __syncthreads();
#pragma unroll 4
    for (int c = 0; c < 32; ++c) {
      float2 T0 = ((float2*)Tw)[c * 64 + tx];
      float2 T1 = ((float2*)Tw)[c * 64 + tx + 32];
#pragma unroll
      for (int j = 0; j < 8; ++j) {
        float2 Yv = ((float2*)Ys)[c * 65 + ty + 8 * j];
        acc0[j] = fmaf(Yv.x, T0.x, acc0[j]);
        acc0[j] = fmaf(-Yv.y, T0.y, acc0[j]);
        acc1[j] = fmaf(Yv.x, T1.x, acc1[j]);
        acc1[j] = fmaf(-Yv.y, T1.y, acc1[j]);
      }
    }
  }
#pragma unroll
  for (int j = 0; j < 8; ++j) {
    int m = m0 + ty + 8 * j;
    SW[((size_t)k * D1 + m) * D1 + n0 + tx] = acc0[j];
    SW[((size_t)k * D1 + m) * D1 + n0 + tx + 32] = acc1[j];
  }
}

// ---------------- conv: per-batch 3x3 grouped conv -----------------------
// w[b][oc][ic][dy][dx] = sum_k att[b,k] * SW[k][oc*3+dy][ic*3+dx]
__global__ __launch_bounds__(256) void conv_kernel(
    const float* __restrict__ x, const float* __restrict__ ka,
    const float* __restrict__ SW, float* __restrict__ out) {
  __shared__ float xs[66 * 67];
  __shared__ float wls[36];
  __shared__ float attL[4];
  int t = threadIdx.x;
  int oc0 = blockIdx.x * 4;
  int b = blockIdx.y;
  if (t < 4) attL[t] = 0.5f / (1.f + expf(-ka[b * 4 + t]));
  __syncthreads();
  float att0 = attL[0], att1 = attL[1], att2 = attL[2], att3 = attL[3];
  int y = t >> 2;
  int xb = (t & 3) << 4;
  float acc[4][16];
#pragma unroll
  for (int o = 0; o < 4; ++o)
#pragma unroll
    for (int p = 0; p < 16; ++p) acc[o][p] = 0.f;

  for (int ic = 0; ic < NC; ++ic) {
    __syncthreads();
    const float* xp = x + ((size_t)(b * NC + ic)) * 4096;
#pragma unroll
    for (int p = 0; p < 18; ++p) {  // zero-padded 66x66 halo tile
      int idx = t + 256 * p;
      if (idx < 4356) {
        int row = idx / 66;
        int col = idx - row * 66;
        int gy = row - 1, gx = col - 1;
        float v = 0.f;
        if ((unsigned)gy < 64u && (unsigned)gx < 64u) v = xp[gy * 64 + gx];
        xs[row * 67 + col] = v;
      }
    }
    if (t < 36) {  // combine 4 kernel templates into this batch's weights
      int oci = t / 9, r = t - oci * 9;
      int dy = r / 3, dx = r - dy * 3;
      size_t base = (size_t)((oc0 + oci) * 3 + dy) * D1 + (ic * 3 + dx);
      float wv = att0 * SW[base] + att1 * SW[base + 589824] +
                 att2 * SW[base + 2 * 589824] + att3 * SW[base + 3 * 589824];
      wls[t] = wv;
    }
    __syncthreads();
    float w[4][9];
#pragma unroll
    for (int o = 0; o < 4; ++o)
#pragma unroll
      for (int r = 0; r < 9; ++r) w[o][r] = wls[o * 9 + r];
    float cA[3], cB[3], cC[3];
#pragma unroll
    for (int r = 0; r < 3; ++r) {
      cA[r] = xs[(y + r) * 67 + xb];
      cB[r] = xs[(y + r) * 67 + xb + 1];
    }
#pragma unroll
    for (int px = 0; px < 16; ++px) {
#pragma unroll
      for (int r = 0; r < 3; ++r) cC[r] = xs[(y + r) * 67 + xb + px + 2];
#pragma unroll
      for (int o = 0; o < 4; ++o) {
        float s = acc[o][px];
#pragma unroll
        for (int r = 0; r < 3; ++r) {
          s = fmaf(w[o][r * 3 + 0], cA[r], s);
          s = fmaf(w[o][r * 3 + 1], cB[r], s);
          s = fmaf(w[o][r * 3 + 2], cC[r], s);
        }
        acc[o][px] = s;
      }
#pragma unroll
      for (int r = 0; r < 3; ++r) {
        cA[r] = cB[r];
        cB[r] = cC[r];
      }
    }
  }
#pragma unroll
  for (int o = 0; o < 4; ++o) {
    size_t base = (((size_t)b * NC + oc0 + o) * 64 + y) * 64 + xb;
#pragma unroll
    for (int px = 0; px < 16; ++px) out[base + px] = acc[o][px];
  }
}

extern "C" void kernel_launch(void* const* d_in, const int* in_sizes, int n_in,
                              void* d_out, int out_size, void* d_ws,
                              size_t ws_size, hipStream_t stream) {
  const float* x = (const float*)d_in[0];
  const float* dw = (const float*)d_in[1];
  const float* ka = (const float*)d_in[2];
  const int* fh = (const int*)d_in[3];
  const int* fw = (const int*)d_in[4];
  float* out = (float*)d_out;
  float* bufA = (float*)d_ws;             // spec, later SW
  float* bufY = bufA + SPEC_FLOATS;       // stage-A output

  hipLaunchKernelGGL(scatter_kernel, dim3(1155, KNUM), dim3(256), 0, stream,
                     dw, fh, fw, bufA);
  hipLaunchKernelGGL(stageA_kernel, dim3(13, 12, KNUM), dim3(256), 0, stream,
                     bufA, bufY);
  hipLaunchKernelGGL(stageB_kernel, dim3(12, 12, KNUM), dim3(256), 0, stream,
                     bufY, bufA);
  hipLaunchKernelGGL(conv_kernel, dim3(64, NB), dim3(256), 0, stream, x, ka,
                     bufA, out);
}

// Round 2
// 942.544 us; speedup vs baseline: 2.4198x; 2.4198x over previous
//
#include <hip/hip_runtime.h>
#include <math.h>

#define D1 768
#define D2R 385
#define NF 295680   // 768*385
#define KNUM 4
#define NB 8
#define NC 256
#define HW 64

// ws layout (floats):
//   bufA [0 .. 2365440)  : scattered spectrum (4,768,385) complex; reused as SW (4,768,768) real
//   bufY [2365440 .. )   : stage-A output (4,768,385) complex
#define SPEC_FLOATS 2365440

// ---------------- scatter: dft_weight -> dense half-spectrum -------------
__global__ __launch_bounds__(256) void scatter_kernel(
    const float* __restrict__ dw, const int* __restrict__ fh,
    const int* __restrict__ fw, float* __restrict__ spec) {
  int i = blockIdx.x * 256 + threadIdx.x;  // 0..NF-1 (grid.x = 1155 exact)
  int k = blockIdx.y;
  const float2 v = ((const float2*)dw)[(size_t)k * NF + i];
  int h = fh[i], w = fw[i];
  ((float2*)spec)[((size_t)k * D1 + h) * D2R + w] = v;
}

// ---------------- stage A: complex ifft along axis 0 (length 768) --------
// Y[k][m][c] = (wgt_c/768^2) * sum_h spec[k][h][c] * e^{+2pi i h m/768}
__global__ __launch_bounds__(256) void stageA_kernel(
    const float* __restrict__ spec, float* __restrict__ Y) {
  __shared__ float Es[32 * 64 * 2];  // [h][m] complex
  __shared__ float Ss[32 * 32 * 2];  // [h][c] complex
  int t = threadIdx.x;
  int c0 = blockIdx.x * 32;
  int m0 = blockIdx.y * 64;
  int k = blockIdx.z;
  int tx = t & 31, ty = t >> 5;
  float accre[8] = {0.f, 0.f, 0.f, 0.f, 0.f, 0.f, 0.f, 0.f};
  float accim[8] = {0.f, 0.f, 0.f, 0.f, 0.f, 0.f, 0.f, 0.f};

  for (int kt = 0; kt < 24; ++kt) {
    int h0 = kt * 32;
    __syncthreads();
#pragma unroll
    for (int p = 0; p < 4; ++p) {  // load S tile (32h x 32c)
      int idx = t + 256 * p;
      int h = idx >> 5, c = idx & 31;
      float2 v = make_float2(0.f, 0.f);
      if (c0 + c < D2R)
        v = ((const float2*)spec)[((size_t)k * D1 + h0 + h) * D2R + c0 + c];
      ((float2*)Ss)[h * 32 + c] = v;
    }
#pragma unroll
    for (int p = 0; p < 8; ++p) {  // generate E tile (32h x 64m)
      int idx = t + 256 * p;
      int h = idx >> 6, m = idx & 63;
      int tt = ((h0 + h) * (m0 + m)) % 768;
      float th = (float)tt * 0.008181230868723419f;  // 2pi/768
      float s, c2;
      sincosf(th, &s, &c2);
      ((float2*)Es)[h * 64 + m] = make_float2(c2, s);
    }
    __syncthreads();
#pragma unroll 4
    for (int h = 0; h < 32; ++h) {
      float2 S = ((float2*)Ss)[h * 32 + tx];
#pragma unroll
      for (int j = 0; j < 8; ++j) {
        float2 E = ((float2*)Es)[h * 64 + ty + 8 * j];
        accre[j] = fmaf(S.x, E.x, accre[j]);
        accre[j] = fmaf(-S.y, E.y, accre[j]);
        accim[j] = fmaf(S.x, E.y, accim[j]);
        accim[j] = fmaf(S.y, E.x, accim[j]);
      }
    }
  }
  int c = c0 + tx;
  if (c < D2R) {
    // fold irfft Hermitian weights (2 for interior bins) and 1/768^2
    float scale = (c == 0 || c == D2R - 1) ? 1.6954210069444445e-6f
                                           : 3.390842013888889e-6f;
#pragma unroll
    for (int j = 0; j < 8; ++j) {
      int m = m0 + ty + 8 * j;
      ((float2*)Y)[((size_t)k * D1 + m) * D2R + c] =
          make_float2(accre[j] * scale, accim[j] * scale);
    }
  }
}

// ---------------- stage B: real irfft along axis 1 (385 -> 768) ----------
// SW[k][m][n] = sum_c ( ReY'[m][c] cos(2pi c n/768) - ImY'[m][c] sin(...) )
__global__ __launch_bounds__(256) void stageB_kernel(
    const float* __restrict__ Y, float* __restrict__ SW) {
  __shared__ float Ys[32 * 65 * 2];  // [c][m] complex, padded stride 65
  __shared__ float Tw[32 * 64 * 2];  // [c][n] (cos, sin)
  int t = threadIdx.x;
  int n0 = blockIdx.x * 64;
  int m0 = blockIdx.y * 64;
  int k = blockIdx.z;
  int tx = t & 31, ty = t >> 5;
  float acc0[8] = {0.f, 0.f, 0.f, 0.f, 0.f, 0.f, 0.f, 0.f};
  float acc1[8] = {0.f, 0.f, 0.f, 0.f, 0.f, 0.f, 0.f, 0.f};

  for (int kt = 0; kt < 13; ++kt) {
    int cb = kt * 32;
    __syncthreads();
#pragma unroll
    for (int p = 0; p < 8; ++p) {  // load Y tile transposed -> [c][m]
      int idx = t + 256 * p;
      int m = idx >> 5, c = idx & 31;
      float2 v = make_float2(0.f, 0.f);
      if (cb + c < D2R)
        v = ((const float2*)Y)[((size_t)k * D1 + m0 + m) * D2R + cb + c];
      ((float2*)Ys)[c * 65 + m] = v;
    }
#pragma unroll
    for (int p = 0; p < 8; ++p) {  // generate twiddle tile [c][n]
      int idx = t + 256 * p;
      int c = idx >> 6, n = idx & 63;
      int tt = ((cb + c) * (n0 + n)) % 768;
      float th = (float)tt * 0.008181230868723419f;
      float s, cc;
      sincosf(th, &s, &cc);
      ((float2*)Tw)[c * 64 + n] = make_float2(cc, s);
    }
    __syncthreads();
#pragma unroll 4
    for (int c = 0; c < 32; ++c) {
      float2 T0 = ((float2*)Tw)[c * 64 + tx];
      float2 T1 = ((float2*)Tw)[c * 64 + tx + 32];
#pragma unroll
      for (int j = 0; j < 8; ++j) {
        float2 Yv = ((float2*)Ys)[c * 65 + ty + 8 * j];
        acc0[j] = fmaf(Yv.x, T0.x, acc0[j]);
        acc0[j] = fmaf(-Yv.y, T0.y, acc0[j]);
        acc1[j] = fmaf(Yv.x, T1.x, acc1[j]);
        acc1[j] = fmaf(-Yv.y, T1.y, acc1[j]);
      }
    }
  }
#pragma unroll
  for (int j = 0; j < 8; ++j) {
    int m = m0 + ty + 8 * j;
    SW[((size_t)k * D1 + m) * D1 + n0 + tx] = acc0[j];
    SW[((size_t)k * D1 + m) * D1 + n0 + tx + 32] = acc1[j];
  }
}

// ---------------- conv: per-batch 3x3 grouped conv -----------------------
// w[b][oc][ic][dy][dx] = sum_k att[b,k] * SW[k][oc*3+dy][ic*3+dx]
// Pipeline: register-prefetch x tile for ic+1 while computing ic; all
// combined weights precomputed into LDS once per block.
__global__ __launch_bounds__(256, 2) void conv_kernel(
    const float* __restrict__ x, const float* __restrict__ ka,
    const float* __restrict__ SW, float* __restrict__ out) {
  __shared__ __align__(16) float xs[66 * 67];       // halo tile, stride 67
  __shared__ __align__(16) float wAll[256 * 36];    // per-ic combined weights
  int t = threadIdx.x;
  int oc0 = blockIdx.x * 4;
  int b = blockIdx.y;

  float att0 = 0.5f / (1.f + expf(-ka[b * 4 + 0]));
  float att1 = 0.5f / (1.f + expf(-ka[b * 4 + 1]));
  float att2 = 0.5f / (1.f + expf(-ka[b * 4 + 2]));
  float att3 = 0.5f / (1.f + expf(-ka[b * 4 + 3]));

  // ---- one-time: zero xs (sets the padding halo; interior overwritten) ----
  for (int idx = t; idx < 66 * 67; idx += 256) xs[idx] = 0.f;

  // ---- one-time: combine 4 kernel templates for ALL ic into LDS ----
  for (int idx = t; idx < 256 * 36; idx += 256) {
    int ic = idx / 36;
    int r = idx - ic * 36;
    int oci = r / 9;
    int rr = r - oci * 9;
    int dy = rr / 3, dx = rr - dy * 3;
    size_t base = (size_t)((oc0 + oci) * 3 + dy) * D1 + (ic * 3 + dx);
    wAll[idx] = att0 * SW[base] + att1 * SW[base + 589824] +
                att2 * SW[base + 2 * 589824] + att3 * SW[base + 3 * 589824];
  }

  // ---- thread roles ----
  int row = t >> 2;            // 0..63  (staging row; also output row y)
  int cq = (t & 3) << 4;       // 0,16,32,48 (column quarter)
  const float4* gp =
      (const float4*)(x + (size_t)b * NC * 4096) + row * 16 + (cq >> 2);
  float* wrp = &xs[(row + 1) * 67 + 1 + cq];

  float acc[4][16];
#pragma unroll
  for (int o = 0; o < 4; ++o)
#pragma unroll
    for (int p = 0; p < 16; ++p) acc[o][p] = 0.f;

  // prefetch ic = 0
  float4 p0 = gp[0], p1 = gp[1], p2 = gp[2], p3 = gp[3];

  for (int ic = 0; ic < NC; ++ic) {
    __syncthreads();  // previous compute done reading xs (ic=0: init done)
    wrp[0] = p0.x;  wrp[1] = p0.y;  wrp[2] = p0.z;  wrp[3] = p0.w;
    wrp[4] = p1.x;  wrp[5] = p1.y;  wrp[6] = p1.z;  wrp[7] = p1.w;
    wrp[8] = p2.x;  wrp[9] = p2.y;  wrp[10] = p2.z; wrp[11] = p2.w;
    wrp[12] = p3.x; wrp[13] = p3.y; wrp[14] = p3.z; wrp[15] = p3.w;
    __syncthreads();

    if (ic < NC - 1) {  // issue next tile's global loads early
      const float4* g2 = gp + (size_t)(ic + 1) * 1024;
      p0 = g2[0]; p1 = g2[1]; p2 = g2[2]; p3 = g2[3];
    }

    // broadcast weights for this ic (9 x ds_read_b128, wave-uniform addr)
    float4 wv[9];
#pragma unroll
    for (int j = 0; j < 9; ++j) wv[j] = ((const float4*)wAll)[ic * 9 + j];
    const float* w = (const float*)wv;  // w[o*9 + r*3 + col]

    float cA[3], cB[3], cC[3];
#pragma unroll
    for (int r = 0; r < 3; ++r) {
      cA[r] = xs[(row + r) * 67 + cq];
      cB[r] = xs[(row + r) * 67 + cq + 1];
    }
#pragma unroll
    for (int px = 0; px < 16; ++px) {
#pragma unroll
      for (int r = 0; r < 3; ++r) cC[r] = xs[(row + r) * 67 + cq + px + 2];
#pragma unroll
      for (int o = 0; o < 4; ++o) {
        float s = acc[o][px];
#pragma unroll
        for (int r = 0; r < 3; ++r) {
          s = fmaf(w[o * 9 + r * 3 + 0], cA[r], s);
          s = fmaf(w[o * 9 + r * 3 + 1], cB[r], s);
          s = fmaf(w[o * 9 + r * 3 + 2], cC[r], s);
        }
        acc[o][px] = s;
      }
#pragma unroll
      for (int r = 0; r < 3; ++r) {
        cA[r] = cB[r];
        cB[r] = cC[r];
      }
    }
  }

#pragma unroll
  for (int o = 0; o < 4; ++o) {
    size_t base = (((size_t)b * NC + oc0 + o) * 64 + row) * 64 + cq;
    float4* op = (float4*)(out + base);
    op[0] = make_float4(acc[o][0], acc[o][1], acc[o][2], acc[o][3]);
    op[1] = make_float4(acc[o][4], acc[o][5], acc[o][6], acc[o][7]);
    op[2] = make_float4(acc[o][8], acc[o][9], acc[o][10], acc[o][11]);
    op[3] = make_float4(acc[o][12], acc[o][13], acc[o][14], acc[o][15]);
  }
}

extern "C" void kernel_launch(void* const* d_in, const int* in_sizes, int n_in,
                              void* d_out, int out_size, void* d_ws,
                              size_t ws_size, hipStream_t stream) {
  const float* x = (const float*)d_in[0];
  const float* dw = (const float*)d_in[1];
  const float* ka = (const float*)d_in[2];
  const int* fh = (const int*)d_in[3];
  const int* fw = (const int*)d_in[4];
  float* out = (float*)d_out;
  float* bufA = (float*)d_ws;             // spec, later SW
  float* bufY = bufA + SPEC_FLOATS;       // stage-A output

  hipLaunchKernelGGL(scatter_kernel, dim3(1155, KNUM), dim3(256), 0, stream,
                     dw, fh, fw, bufA);
  hipLaunchKernelGGL(stageA_kernel, dim3(13, 12, KNUM), dim3(256), 0, stream,
                     bufA, bufY);
  hipLaunchKernelGGL(stageB_kernel, dim3(12, 12, KNUM), dim3(256), 0, stream,
                     bufY, bufA);
  hipLaunchKernelGGL(conv_kernel, dim3(64, NB), dim3(256), 0, stream, x, ka,
                     bufA, out);
}